// Round 12
// baseline (537.815 us; speedup 1.0000x reference)
//
#include <hip/hip_runtime.h>

typedef unsigned short u16;
typedef unsigned int u32;
typedef __attribute__((ext_vector_type(8))) short bf16x8;
typedef __attribute__((ext_vector_type(4))) float f32x4;

#define DEVI static __device__ __forceinline__

DEVI u16 f2bf(float f) {
  u32 u = __float_as_uint(f);
  return (u16)((u + 0x7fffu + ((u >> 16) & 1u)) >> 16);
}
DEVI float bf2f(u16 h) { return __uint_as_float(((u32)h) << 16); }

union bfr8 { u16 u[8]; u32 w[4]; bf16x8 v; };

// dims: B=4, L=1024, HID=1024, H=16, DH=64, BH=64
// d_out: out[4096][1024] f32, then scores[64][1024][1024] f32.
// bias1 (bf16, pre-scaled by 0.125) is packed into the LOW half (first 2KB)
// of each 4KB scores row; k_qkpv consumes it in DESCENDING r-tile order so
// the f32 final-score writes never clobber unread bias1.

// ---------------- K1: QKV projection, all three in one launch (z=0,1,2) ----
__global__ __launch_bounds__(256) void k_proj(
    const float* __restrict__ Xq, const float* __restrict__ Xv,
    const float* __restrict__ Wq, const float* __restrict__ bq,
    const float* __restrict__ Wk, const float* __restrict__ bk,
    const float* __restrict__ Wv, const float* __restrict__ bv,
    u16* __restrict__ Qbh, u16* __restrict__ Qlb,
    u16* __restrict__ Kbh, u16* __restrict__ Klb,
    u16* __restrict__ Vt)
{
  const int zmode = blockIdx.z;
  const float* X; const float* W; const float* bias; u16* Obh; u16* Olb;
  if (zmode == 0)      { X = Xq; W = Wq; bias = bq; Obh = Qbh; Olb = Qlb; }
  else if (zmode == 1) { X = Xv; W = Wk; bias = bk; Obh = Kbh; Olb = Klb; }
  else                 { X = Xv; W = Wv; bias = bv; Obh = Vt;  Olb = 0;   }

  __shared__ __align__(16) u16 sm[2 * 128 * 72];
  u16* As = sm;
  u16* Bs = sm + 128 * 72;
  const int t = threadIdx.x, w = t >> 6, lane = t & 63, g = lane >> 4, lr = lane & 15;
  const int n0 = blockIdx.x * 128, o0 = blockIdx.y * 128;
  const int wr = w >> 1, wc = w & 1;
  f32x4 acc[4][4] = {};
  for (int k0 = 0; k0 < 1024; k0 += 64) {
    for (int p = 0; p < 8; ++p) {
      int fi = t + p * 256, row = fi >> 4, c4 = (fi & 15) * 4;
      float4 v = *reinterpret_cast<const float4*>(X + (size_t)(n0 + row) * 1024 + k0 + c4);
      u16* d = As + row * 72 + c4;
      d[0] = f2bf(v.x); d[1] = f2bf(v.y); d[2] = f2bf(v.z); d[3] = f2bf(v.w);
    }
    for (int p = 0; p < 8; ++p) {
      int fi = t + p * 256, row = fi >> 4, c4 = (fi & 15) * 4;
      float4 v = *reinterpret_cast<const float4*>(W + (size_t)(o0 + row) * 1024 + k0 + c4);
      u16* d = Bs + row * 72 + c4;
      d[0] = f2bf(v.x); d[1] = f2bf(v.y); d[2] = f2bf(v.z); d[3] = f2bf(v.w);
    }
    __syncthreads();
    #pragma unroll
    for (int ks = 0; ks < 2; ++ks) {
      bf16x8 af[4], bfr[4];
      #pragma unroll
      for (int fm = 0; fm < 4; ++fm)
        af[fm] = *reinterpret_cast<const bf16x8*>(As + (wr * 64 + fm * 16 + lr) * 72 + ks * 32 + g * 8);
      #pragma unroll
      for (int fn = 0; fn < 4; ++fn)
        bfr[fn] = *reinterpret_cast<const bf16x8*>(Bs + (wc * 64 + fn * 16 + lr) * 72 + ks * 32 + g * 8);
      #pragma unroll
      for (int fm = 0; fm < 4; ++fm)
        #pragma unroll
        for (int fn = 0; fn < 4; ++fn)
          acc[fm][fn] = __builtin_amdgcn_mfma_f32_16x16x32_bf16(af[fm], bfr[fn], acc[fm][fn], 0, 0, 0);
    }
    __syncthreads();
  }
  float bv_[4];
  #pragma unroll
  for (int fn = 0; fn < 4; ++fn) bv_[fn] = bias[o0 + wc * 64 + fn * 16 + lr];
  u16* stg = sm + w * (64 * 72);
  if (zmode < 2) {
    #pragma unroll
    for (int fm = 0; fm < 4; ++fm)
      #pragma unroll
      for (int fn = 0; fn < 4; ++fn)
        #pragma unroll
        for (int i = 0; i < 4; ++i)
          stg[(fm * 16 + g * 4 + i) * 72 + fn * 16 + lr] = f2bf(acc[fm][fn][i] + bv_[fn]);
    __syncthreads();
    const int n = n0 + wr * 64 + lane;
    const int b = n >> 10, l = n & 1023;
    const int h = (o0 + wc * 64) >> 6;
    const int bh = b * 16 + h;
    const u16* prow = stg + lane * 72;
    u16* obh = Obh + ((size_t)bh << 16) + ((size_t)l << 6);
    u16* olb = Olb + ((size_t)l << 12) + ((size_t)bh << 6);
    #pragma unroll
    for (int c = 0; c < 8; ++c) {
      uint4 vv = *reinterpret_cast<const uint4*>(prow + c * 8);
      *reinterpret_cast<uint4*>(obh + c * 8) = vv;
      *reinterpret_cast<uint4*>(olb + c * 8) = vv;
    }
  } else {
    #pragma unroll
    for (int fm = 0; fm < 4; ++fm)
      #pragma unroll
      for (int fn = 0; fn < 4; ++fn)
        #pragma unroll
        for (int i = 0; i < 4; ++i)
          stg[(fn * 16 + lr) * 72 + fm * 16 + g * 4 + i] = f2bf(acc[fm][fn][i] + bv_[fn]);
    __syncthreads();
    const int nb = n0 + wr * 64;
    const int b = nb >> 10, l0w = nb & 1023;
    const int h = (o0 + wc * 64) >> 6;
    const int bh = b * 16 + h;
    const u16* prow = stg + lane * 72;
    u16* ovt = Obh + ((size_t)bh << 16) + ((size_t)lane << 10) + l0w;
    #pragma unroll
    for (int c = 0; c < 8; ++c)
      *reinterpret_cast<uint4*>(ovt + c * 8) = *reinterpret_cast<const uint4*>(prow + c * 8);
  }
}

// ---------------- K2: bias kernels merged in ONE launch (R8 version) -------
// mode = bid&1.  mode 0 (qS): per l, S[l] (1024r x 64d) @ Qlb[l]^T
//   -> bias1[bh][l][r] bf16 *0.125 (packed low-half of scores rows).
// mode 1 (kS): per r, S[:,r,:] (1024l x 64d) @ Klb[r]^T -> TB2[bh][r][l] raw.
__global__ __launch_bounds__(256, 3) void k_biasqk(
    const float* __restrict__ S, const u16* __restrict__ Qlb,
    const u16* __restrict__ Klb, u16* __restrict__ bias1,
    u16* __restrict__ TB2)
{
  __shared__ __align__(16) u16 Bsm[64 * 72];
  __shared__ __align__(16) u16 stg[64 * 264];
  const int t = threadIdx.x, w = t >> 6, lane = t & 63, g = lane >> 4, lr = lane & 15;
  const int bid = blockIdx.x;
  const int mode = bid & 1, rest = bid >> 1;
  const int tile0 = (rest & 3) * 256;       // r0 (mode 0) or l0 (mode 1)
  const int fix = rest >> 2;                // l (mode 0) or r (mode 1)

  {
    const u16* Bp = (mode == 0 ? Qlb : Klb) + (size_t)fix * 4096;
    #pragma unroll
    for (int p = 0; p < 2; ++p) {
      int ci = t + p * 256, row = ci >> 3, c8 = (ci & 7) * 8;
      *reinterpret_cast<uint4*>(Bsm + row * 72 + c8) =
          *reinterpret_cast<const uint4*>(Bp + row * 64 + c8);
    }
  }
  __syncthreads();
  f32x4 acc[4][4] = {};
  #pragma unroll
  for (int ks = 0; ks < 2; ++ks) {
    float4 ld[8];
    #pragma unroll
    for (int fm = 0; fm < 4; ++fm) {
      const float* p = (mode == 0)
        ? S + ((size_t)fix * 1024 + tile0 + w * 64 + fm * 16 + lr) * 64 + ks * 32 + g * 8
        : S + ((size_t)(tile0 + w * 64 + fm * 16 + lr) << 16) + (size_t)fix * 64 + ks * 32 + g * 8;
      ld[fm * 2 + 0] = *reinterpret_cast<const float4*>(p);
      ld[fm * 2 + 1] = *reinterpret_cast<const float4*>(p + 4);
    }
    bf16x8 af[4], bo[4];
    #pragma unroll
    for (int fm = 0; fm < 4; ++fm) {
      bfr8 u;
      u.u[0] = f2bf(ld[fm * 2].x);     u.u[1] = f2bf(ld[fm * 2].y);
      u.u[2] = f2bf(ld[fm * 2].z);     u.u[3] = f2bf(ld[fm * 2].w);
      u.u[4] = f2bf(ld[fm * 2 + 1].x); u.u[5] = f2bf(ld[fm * 2 + 1].y);
      u.u[6] = f2bf(ld[fm * 2 + 1].z); u.u[7] = f2bf(ld[fm * 2 + 1].w);
      af[fm] = u.v;
    }
    #pragma unroll
    for (int fn = 0; fn < 4; ++fn)
      bo[fn] = *reinterpret_cast<const bf16x8*>(Bsm + (fn * 16 + lr) * 72 + ks * 32 + g * 8);
    #pragma unroll
    for (int fm = 0; fm < 4; ++fm)
      #pragma unroll
      for (int fn = 0; fn < 4; ++fn)
        acc[fm][fn] = __builtin_amdgcn_mfma_f32_16x16x32_bf16(af[fm], bo[fn], acc[fm][fn], 0, 0, 0);
  }
  const float scl = (mode == 0) ? 0.125f : 1.0f;
  #pragma unroll
  for (int fm = 0; fm < 4; ++fm)
    #pragma unroll
    for (int fn = 0; fn < 4; ++fn)
      #pragma unroll
      for (int i = 0; i < 4; ++i)
        stg[(fn * 16 + lr) * 264 + w * 64 + fm * 16 + g * 4 + i] = f2bf(acc[fm][fn][i] * scl);
  __syncthreads();
  {
    const int bh = t >> 2, seg = t & 3;
    u16* dst = (mode == 0)
      ? bias1 + ((size_t)bh << 21) + ((size_t)fix << 11) + tile0 + seg * 64
      : TB2 + ((size_t)bh << 20) + ((size_t)fix << 10) + tile0 + seg * 64;
    const u16* src = stg + bh * 264 + seg * 64;
    #pragma unroll
    for (int j = 0; j < 8; ++j)
      *reinterpret_cast<uint4*>(dst + j * 8) = *reinterpret_cast<const uint4*>(src + j * 8);
  }
}

// ---------------- K3: qk + bias merge + softmax + PV (KVBLK=64, v2) --------
// one block per (bh, 32-l tile); r-tiles of 64 DESCENDING (bias1 packing).
// LDS ~33 KB -> 4 blocks/CU (was 60 KB -> 2): occupancy-driven rewrite.
// scores = (q.k + kS)*0.125 + bias1(prescaled) + mask  -> written to d_out.
// P = exp(scores); ctx = (sum P*V)/(sum P); PV A-frags direct from the QK
// accumulator layout: A slot j: r = wr*32 + (j>>2)*16 + g*4 + (j&3).
__global__ __launch_bounds__(256) void k_qkpv(
    const u16* __restrict__ Qbh, const u16* __restrict__ Kbh,
    const u16* __restrict__ TB2, const u16* __restrict__ Vt,
    const float* __restrict__ mask, float* __restrict__ scores,
    u16* __restrict__ ctx)
{
  __shared__ __align__(16) u16 Qs[32 * 72];    // 4.6 KB
  __shared__ __align__(16) u16 Ksm[64 * 72];   // 9.2 KB ; ctx f32 [32][66] in epilogue
  __shared__ __align__(16) u16 T2s[64 * 40];   // 5.1 KB ; ctx bf16 [32][64] in epilogue
  __shared__ __align__(16) u16 B1s[32 * 72];   // 4.6 KB
  __shared__ __align__(16) u16 Vs[64 * 72];    // 9.2 KB  V transposed: [dh][r-tile 64]
  __shared__ float reds[32];
  __shared__ float ssum[32];
  const int t = threadIdx.x, w = t >> 6, lane = t & 63, g = lane >> 4, lr = lane & 15;
  const int bid = blockIdx.x;
  const int swz = (bid & 7) * 256 + (bid >> 3);   // XCD-chunked: same bh on one XCD
  const int bh = swz >> 5, l0 = (swz & 31) << 5;
  const u16* scores_u16 = reinterpret_cast<const u16*>(scores);
  {
    const u16* Qp = Qbh + ((size_t)bh << 16) + ((size_t)l0 << 6);
    int row = t >> 3, c8 = (t & 7) * 8;
    *reinterpret_cast<uint4*>(Qs + row * 72 + c8) =
        *reinterpret_cast<const uint4*>(Qp + (size_t)row * 64 + c8);
  }
  const int wr = w & 1, wc = w >> 1;
  const int l = l0 + wc * 16 + lr;
  const float* mrow = mask + ((size_t)(bh >> 4) << 10);
  float s = 0.f;
  f32x4 apv[4] = {};   // ctx partial: l = wc*16+g*4+i, dh = n*16+lr
  for (int r0 = 960; r0 >= 0; r0 -= 64) {
    {
      const u16* Kp = Kbh + ((size_t)bh << 16) + ((size_t)r0 << 6);
      #pragma unroll
      for (int p = 0; p < 2; ++p) {
        int ci = t + p * 256, row = ci >> 3, c8 = (ci & 7) * 8;
        *reinterpret_cast<uint4*>(Ksm + row * 72 + c8) =
            *reinterpret_cast<const uint4*>(Kp + (size_t)row * 64 + c8);
      }
    }
    {
      int row = t >> 2, c8 = (t & 3) * 8;
      *reinterpret_cast<uint4*>(T2s + row * 40 + c8) =
          *reinterpret_cast<const uint4*>(TB2 + ((size_t)bh << 20) + ((size_t)(r0 + row) << 10) + l0 + c8);
    }
    {
      int row = t >> 3, c8 = (t & 7) * 8;
      *reinterpret_cast<uint4*>(B1s + row * 72 + c8) =
          *reinterpret_cast<const uint4*>(scores_u16 + ((size_t)bh << 21) + ((size_t)(l0 + row) << 11) + r0 + c8);
    }
    {
      #pragma unroll
      for (int p = 0; p < 2; ++p) {
        int ci = t + p * 256, row = ci >> 3, c8 = (ci & 7) * 8;
        *reinterpret_cast<uint4*>(Vs + row * 72 + c8) =
            *reinterpret_cast<const uint4*>(Vt + ((size_t)bh << 16) + ((size_t)row << 10) + r0 + c8);
      }
    }
    __syncthreads();
    f32x4 acc[2] = {};
    #pragma unroll
    for (int ks = 0; ks < 2; ++ks) {
      bf16x8 bq = *reinterpret_cast<const bf16x8*>(Qs + (wc * 16 + lr) * 72 + ks * 32 + g * 8);
      #pragma unroll
      for (int fm = 0; fm < 2; ++fm) {
        bf16x8 ak = *reinterpret_cast<const bf16x8*>(Ksm + (wr * 32 + fm * 16 + lr) * 72 + ks * 32 + g * 8);
        acc[fm] = __builtin_amdgcn_mfma_f32_16x16x32_bf16(ak, bq, acc[fm], 0, 0, 0);
      }
    }
    float* srow = scores + ((size_t)bh << 20) + ((size_t)l << 10);
    u32 pL[2], pH[2];
    #pragma unroll
    for (int fm = 0; fm < 2; ++fm) {
      int rloc = wr * 32 + fm * 16 + g * 4;
      int rbase = r0 + rloc;
      float4 mv = *reinterpret_cast<const float4*>(mrow + rbase);
      float b20 = bf2f(T2s[(rloc + 0) * 40 + wc * 16 + lr]);
      float b21 = bf2f(T2s[(rloc + 1) * 40 + wc * 16 + lr]);
      float b22 = bf2f(T2s[(rloc + 2) * 40 + wc * 16 + lr]);
      float b23 = bf2f(T2s[(rloc + 3) * 40 + wc * 16 + lr]);
      uint2 b1p = *reinterpret_cast<const uint2*>(B1s + (wc * 16 + lr) * 72 + rloc);
      float b10 = bf2f((u16)(b1p.x & 0xffff)), b11 = bf2f((u16)(b1p.x >> 16));
      float b12 = bf2f((u16)(b1p.y & 0xffff)), b13 = bf2f((u16)(b1p.y >> 16));
      float4 o;
      o.x = (acc[fm][0] + b20) * 0.125f + b10 + mv.x;
      o.y = (acc[fm][1] + b21) * 0.125f + b11 + mv.y;
      o.z = (acc[fm][2] + b22) * 0.125f + b12 + mv.z;
      o.w = (acc[fm][3] + b23) * 0.125f + b13 + mv.w;
      *reinterpret_cast<float4*>(srow + rbase) = o;
      float p0 = __expf(o.x), p1 = __expf(o.y), p2 = __expf(o.z), p3 = __expf(o.w);
      s += p0 + p1 + p2 + p3;
      pL[fm] = (u32)f2bf(p0) | ((u32)f2bf(p1) << 16);
      pH[fm] = (u32)f2bf(p2) | ((u32)f2bf(p3) << 16);
    }
    // PV: one mfma per n; A slot j: r = wr*32 + (j>>2)*16 + g*4 + (j&3)
    {
      bfr8 a;
      a.w[0] = pL[0]; a.w[1] = pH[0]; a.w[2] = pL[1]; a.w[3] = pH[1];
      #pragma unroll
      for (int n = 0; n < 4; ++n) {
        const u16* vb = Vs + (n * 16 + lr) * 72 + wr * 32 + g * 4;
        uint2 v0 = *reinterpret_cast<const uint2*>(vb);
        uint2 v1 = *reinterpret_cast<const uint2*>(vb + 16);
        bfr8 b;
        b.w[0] = v0.x; b.w[1] = v0.y; b.w[2] = v1.x; b.w[3] = v1.y;
        apv[n] = __builtin_amdgcn_mfma_f32_16x16x32_bf16(a.v, b.v, apv[n], 0, 0, 0);
      }
    }
    __syncthreads();
  }
  // row-sum reduce: across g within wave, then across wr pair via LDS
  #pragma unroll
  for (int off = 16; off < 64; off <<= 1) s += __shfl_xor(s, off);
  if (wr == 1 && lane < 16) reds[wc * 16 + lr] = s;
  __syncthreads();
  if (wr == 0 && lane < 16) ssum[wc * 16 + lr] = 1.0f / (s + reds[wc * 16 + lr]);
  // ctx cross-wave reduce in LDS (reuse Ksm as f32 [32][66], T2s as bf16 [32][64])
  float* c32 = reinterpret_cast<float*>(Ksm);
  u16* cb = T2s;
  if (wr == 1) {
    #pragma unroll
    for (int n = 0; n < 4; ++n)
      #pragma unroll
      for (int i = 0; i < 4; ++i)
        c32[(wc * 16 + g * 4 + i) * 66 + n * 16 + lr] = apv[n][i];
  }
  __syncthreads();
  if (wr == 0) {
    #pragma unroll
    for (int n = 0; n < 4; ++n)
      #pragma unroll
      for (int i = 0; i < 4; ++i) {
        int li = wc * 16 + g * 4 + i;
        float v = apv[n][i] + c32[li * 66 + n * 16 + lr];
        cb[li * 64 + n * 16 + lr] = f2bf(v * ssum[li]);
      }
  }
  __syncthreads();
  {
    int row = t >> 3, c8 = (t & 7) * 8;
    const int b = bh >> 4, h = bh & 15;
    uint4 vv = *reinterpret_cast<const uint4*>(cb + row * 64 + c8);
    *reinterpret_cast<uint4*>(ctx + ((size_t)(b * 1024 + l0 + row) << 10) + (h << 6) + c8) = vv;
  }
}

// ---------------- K6: out-proj + bias + residual ----------------
__global__ __launch_bounds__(256) void k_outproj(
    const u16* __restrict__ ctx, const float* __restrict__ Wd,
    const float* __restrict__ bd, const float* __restrict__ Xq,
    float* __restrict__ y)
{
  __shared__ __align__(16) u16 As_[128 * 72];
  __shared__ __align__(16) u16 Bs_[128 * 72];
  const int t = threadIdx.x, w = t >> 6, lane = t & 63, g = lane >> 4, lr = lane & 15;
  const int o0 = blockIdx.x * 128, n0 = blockIdx.y * 128;
  const int wr = w >> 1, wc = w & 1;
  f32x4 acc[4][4] = {};
  for (int k0 = 0; k0 < 1024; k0 += 64) {
    for (int p = 0; p < 8; ++p) {
      int fi = t + p * 256, row = fi >> 4, c4 = (fi & 15) * 4;
      float4 v = *reinterpret_cast<const float4*>(Wd + (size_t)(o0 + row) * 1024 + k0 + c4);
      u16* d = As_ + row * 72 + c4;
      d[0] = f2bf(v.x); d[1] = f2bf(v.y); d[2] = f2bf(v.z); d[3] = f2bf(v.w);
    }
    for (int p = 0; p < 4; ++p) {
      int ci = t + p * 256, row = ci >> 3, c8 = (ci & 7) * 8;
      *reinterpret_cast<uint4*>(Bs_ + row * 72 + c8) =
          *reinterpret_cast<const uint4*>(ctx + (size_t)(n0 + row) * 1024 + k0 + c8);
    }
    __syncthreads();
    #pragma unroll
    for (int ks = 0; ks < 2; ++ks) {
      bf16x8 af[4], bfr[4];
      #pragma unroll
      for (int fm = 0; fm < 4; ++fm)
        af[fm] = *reinterpret_cast<const bf16x8*>(As_ + (wr * 64 + fm * 16 + lr) * 72 + ks * 32 + g * 8);
      #pragma unroll
      for (int fn = 0; fn < 4; ++fn)
        bfr[fn] = *reinterpret_cast<const bf16x8*>(Bs_ + (wc * 64 + fn * 16 + lr) * 72 + ks * 32 + g * 8);
      #pragma unroll
      for (int fm = 0; fm < 4; ++fm)
        #pragma unroll
        for (int fn = 0; fn < 4; ++fn)
          acc[fm][fn] = __builtin_amdgcn_mfma_f32_16x16x32_bf16(af[fm], bfr[fn], acc[fm][fn], 0, 0, 0);
    }
    __syncthreads();
  }
  #pragma unroll
  for (int fm = 0; fm < 4; ++fm)
    #pragma unroll
    for (int fn = 0; fn < 4; ++fn) {
      int obase = o0 + wr * 64 + fm * 16 + g * 4;
      int n = n0 + wc * 64 + fn * 16 + lr;
      float4 bb = *reinterpret_cast<const float4*>(bd + obase);
      float4 xx = *reinterpret_cast<const float4*>(Xq + (size_t)n * 1024 + obase);
      float4 o;
      o.x = acc[fm][fn][0] + bb.x + xx.x;
      o.y = acc[fm][fn][1] + bb.y + xx.y;
      o.z = acc[fm][fn][2] + bb.z + xx.z;
      o.w = acc[fm][fn][3] + bb.w + xx.w;
      *reinterpret_cast<float4*>(y + (size_t)n * 1024 + obase) = o;
    }
}

// ---------------- K7: in-place LayerNorm ----------------
__global__ __launch_bounds__(256) void k_ln(
    float* __restrict__ y, const float* __restrict__ gam,
    const float* __restrict__ bet)
{
  __shared__ float red[8];
  const int t = threadIdx.x, w = t >> 6, lane = t & 63;
  float* row = y + ((size_t)blockIdx.x << 10);
  float4 v = *reinterpret_cast<const float4*>(row + t * 4);
  float s1 = v.x + v.y + v.z + v.w;
  float s2 = v.x * v.x + v.y * v.y + v.z * v.z + v.w * v.w;
  #pragma unroll
  for (int s = 1; s < 64; s <<= 1) { s1 += __shfl_xor(s1, s); s2 += __shfl_xor(s2, s); }
  if (lane == 0) { red[w] = s1; red[4 + w] = s2; }
  __syncthreads();
  s1 = red[0] + red[1] + red[2] + red[3];
  s2 = red[4] + red[5] + red[6] + red[7];
  float mu = s1 * (1.0f / 1024.0f);
  float var = s2 * (1.0f / 1024.0f) - mu * mu;
  float rs = rsqrtf(var + 1e-5f);
  float4 gg = *reinterpret_cast<const float4*>(gam + t * 4);
  float4 bb = *reinterpret_cast<const float4*>(bet + t * 4);
  float4 o;
  o.x = (v.x - mu) * rs * gg.x + bb.x;
  o.y = (v.y - mu) * rs * gg.y + bb.y;
  o.z = (v.z - mu) * rs * gg.z + bb.z;
  o.w = (v.w - mu) * rs * gg.w + bb.w;
  *reinterpret_cast<float4*>(row + t * 4) = o;
}

extern "C" void kernel_launch(void* const* d_in, const int* in_sizes, int n_in,
                              void* d_out, int out_size, void* d_ws, size_t ws_size,
                              hipStream_t stream) {
  (void)in_sizes; (void)n_in; (void)out_size; (void)ws_size;
  const float* Xq   = (const float*)d_in[0];
  const float* Xv   = (const float*)d_in[1];
  const float* mask = (const float*)d_in[2];
  const float* S    = (const float*)d_in[3];
  const float* Wq   = (const float*)d_in[4];
  const float* bq   = (const float*)d_in[5];
  const float* Wk   = (const float*)d_in[6];
  const float* bk   = (const float*)d_in[7];
  const float* Wv   = (const float*)d_in[8];
  const float* bv   = (const float*)d_in[9];
  const float* Wd   = (const float*)d_in[10];
  const float* bd   = (const float*)d_in[11];
  const float* gam  = (const float*)d_in[12];
  const float* bet  = (const float*)d_in[13];

  float* out    = (float*)d_out;
  float* scores = out + (size_t)4 * 1024 * 1024;
  u16* scores_u16 = (u16*)scores;

  char* ws = (char*)d_ws;
  u16* Qbh = (u16*)(ws);
  u16* Kbh = (u16*)(ws + ((size_t)8 << 20));
  u16* Vt  = (u16*)(ws + ((size_t)16 << 20));
  u16* Qlb = (u16*)(ws + ((size_t)24 << 20));
  u16* Klb = (u16*)(ws + ((size_t)32 << 20));
  u16* TB2 = (u16*)(ws + ((size_t)40 << 20));
  u16* ctx = (u16*)(ws + ((size_t)169 << 20));

  k_proj<<<dim3(32, 8, 3), 256, 0, stream>>>(Xq, Xv, Wq, bq, Wk, bk, Wv, bv,
                                             Qbh, Qlb, Kbh, Klb, Vt);
  k_biasqk<<<8192, 256, 0, stream>>>(S, Qlb, Klb, scores_u16, TB2);
  k_qkpv<<<2048, 256, 0, stream>>>(Qbh, Kbh, TB2, Vt, mask, scores, ctx);
  k_outproj<<<dim3(8, 32), 256, 0, stream>>>(ctx, Wd, bd, Xq, out);
  k_ln<<<4096, 256, 0, stream>>>(out, gam, bet);
}

// Round 13
// 463.397 us; speedup vs baseline: 1.1606x; 1.1606x over previous
//
#include <hip/hip_runtime.h>

typedef unsigned short u16;
typedef unsigned int u32;
typedef __attribute__((ext_vector_type(8))) short bf16x8;
typedef __attribute__((ext_vector_type(4))) float f32x4;

#define DEVI static __device__ __forceinline__

DEVI u16 f2bf(float f) {
  u32 u = __float_as_uint(f);
  return (u16)((u + 0x7fffu + ((u >> 16) & 1u)) >> 16);
}
DEVI float bf2f(u16 h) { return __uint_as_float(((u32)h) << 16); }

union bfr8 { u16 u[8]; u32 w[4]; bf16x8 v; };

// dims: B=4, L=1024, HID=1024, H=16, DH=64, BH=64
// d_out: out[4096][1024] f32, then scores[64][1024][1024] f32.
// bias1 (bf16, pre-scaled by 0.125) is packed into the LOW half (first 2KB)
// of each 4KB scores row; k_qkpv consumes it in DESCENDING r-tile order so
// the f32 final-score writes never clobber unread bias1.

// ---------------- K1: QKV projection, all three in one launch (z=0,1,2) ----
__global__ __launch_bounds__(256) void k_proj(
    const float* __restrict__ Xq, const float* __restrict__ Xv,
    const float* __restrict__ Wq, const float* __restrict__ bq,
    const float* __restrict__ Wk, const float* __restrict__ bk,
    const float* __restrict__ Wv, const float* __restrict__ bv,
    u16* __restrict__ Qbh, u16* __restrict__ Qlb,
    u16* __restrict__ Kbh, u16* __restrict__ Klb,
    u16* __restrict__ Vt)
{
  const int zmode = blockIdx.z;
  const float* X; const float* W; const float* bias; u16* Obh; u16* Olb;
  if (zmode == 0)      { X = Xq; W = Wq; bias = bq; Obh = Qbh; Olb = Qlb; }
  else if (zmode == 1) { X = Xv; W = Wk; bias = bk; Obh = Kbh; Olb = Klb; }
  else                 { X = Xv; W = Wv; bias = bv; Obh = Vt;  Olb = 0;   }

  __shared__ __align__(16) u16 sm[2 * 128 * 72];
  u16* As = sm;
  u16* Bs = sm + 128 * 72;
  const int t = threadIdx.x, w = t >> 6, lane = t & 63, g = lane >> 4, lr = lane & 15;
  const int n0 = blockIdx.x * 128, o0 = blockIdx.y * 128;
  const int wr = w >> 1, wc = w & 1;
  f32x4 acc[4][4] = {};
  for (int k0 = 0; k0 < 1024; k0 += 64) {
    for (int p = 0; p < 8; ++p) {
      int fi = t + p * 256, row = fi >> 4, c4 = (fi & 15) * 4;
      float4 v = *reinterpret_cast<const float4*>(X + (size_t)(n0 + row) * 1024 + k0 + c4);
      u16* d = As + row * 72 + c4;
      d[0] = f2bf(v.x); d[1] = f2bf(v.y); d[2] = f2bf(v.z); d[3] = f2bf(v.w);
    }
    for (int p = 0; p < 8; ++p) {
      int fi = t + p * 256, row = fi >> 4, c4 = (fi & 15) * 4;
      float4 v = *reinterpret_cast<const float4*>(W + (size_t)(o0 + row) * 1024 + k0 + c4);
      u16* d = Bs + row * 72 + c4;
      d[0] = f2bf(v.x); d[1] = f2bf(v.y); d[2] = f2bf(v.z); d[3] = f2bf(v.w);
    }
    __syncthreads();
    #pragma unroll
    for (int ks = 0; ks < 2; ++ks) {
      bf16x8 af[4], bfr[4];
      #pragma unroll
      for (int fm = 0; fm < 4; ++fm)
        af[fm] = *reinterpret_cast<const bf16x8*>(As + (wr * 64 + fm * 16 + lr) * 72 + ks * 32 + g * 8);
      #pragma unroll
      for (int fn = 0; fn < 4; ++fn)
        bfr[fn] = *reinterpret_cast<const bf16x8*>(Bs + (wc * 64 + fn * 16 + lr) * 72 + ks * 32 + g * 8);
      #pragma unroll
      for (int fm = 0; fm < 4; ++fm)
        #pragma unroll
        for (int fn = 0; fn < 4; ++fn)
          acc[fm][fn] = __builtin_amdgcn_mfma_f32_16x16x32_bf16(af[fm], bfr[fn], acc[fm][fn], 0, 0, 0);
    }
    __syncthreads();
  }
  float bv_[4];
  #pragma unroll
  for (int fn = 0; fn < 4; ++fn) bv_[fn] = bias[o0 + wc * 64 + fn * 16 + lr];
  u16* stg = sm + w * (64 * 72);
  if (zmode < 2) {
    #pragma unroll
    for (int fm = 0; fm < 4; ++fm)
      #pragma unroll
      for (int fn = 0; fn < 4; ++fn)
        #pragma unroll
        for (int i = 0; i < 4; ++i)
          stg[(fm * 16 + g * 4 + i) * 72 + fn * 16 + lr] = f2bf(acc[fm][fn][i] + bv_[fn]);
    __syncthreads();
    const int n = n0 + wr * 64 + lane;
    const int b = n >> 10, l = n & 1023;
    const int h = (o0 + wc * 64) >> 6;
    const int bh = b * 16 + h;
    const u16* prow = stg + lane * 72;
    u16* obh = Obh + ((size_t)bh << 16) + ((size_t)l << 6);
    u16* olb = Olb + ((size_t)l << 12) + ((size_t)bh << 6);
    #pragma unroll
    for (int c = 0; c < 8; ++c) {
      uint4 vv = *reinterpret_cast<const uint4*>(prow + c * 8);
      *reinterpret_cast<uint4*>(obh + c * 8) = vv;
      *reinterpret_cast<uint4*>(olb + c * 8) = vv;
    }
  } else {
    #pragma unroll
    for (int fm = 0; fm < 4; ++fm)
      #pragma unroll
      for (int fn = 0; fn < 4; ++fn)
        #pragma unroll
        for (int i = 0; i < 4; ++i)
          stg[(fn * 16 + lr) * 72 + fm * 16 + g * 4 + i] = f2bf(acc[fm][fn][i] + bv_[fn]);
    __syncthreads();
    const int nb = n0 + wr * 64;
    const int b = nb >> 10, l0w = nb & 1023;
    const int h = (o0 + wc * 64) >> 6;
    const int bh = b * 16 + h;
    const u16* prow = stg + lane * 72;
    u16* ovt = Obh + ((size_t)bh << 16) + ((size_t)lane << 10) + l0w;
    #pragma unroll
    for (int c = 0; c < 8; ++c)
      *reinterpret_cast<uint4*>(ovt + c * 8) = *reinterpret_cast<const uint4*>(prow + c * 8);
  }
}

// ---------------- K2: bias kernels merged, L3-segment-coordinated ----------
// 4 segments of 2048 blocks; segment k covers the S row-slice l in
// [256k, 256k+256) for BOTH modes: mode 0 streams those rows (qS), mode 1
// column-walks the same 64MB slice (kS) -> column reads hit L3 lines the
// row-stream just fetched. mode=sub&1 interleaves the two within a segment.
// mode 0 (qS): per l, S[l] @ Qlb[l]^T -> bias1[bh][l][r] bf16*0.125.
// mode 1 (kS): per r, S[l-tile][r][:] @ Klb[r]^T -> TB2[bh][r][l] raw.
__global__ __launch_bounds__(256, 3) void k_biasqk(
    const float* __restrict__ S, const u16* __restrict__ Qlb,
    const u16* __restrict__ Klb, u16* __restrict__ bias1,
    u16* __restrict__ TB2)
{
  __shared__ __align__(16) u16 Bsm[64 * 72];
  __shared__ __align__(16) u16 stg[64 * 264];
  const int t = threadIdx.x, w = t >> 6, lane = t & 63, g = lane >> 4, lr = lane & 15;
  const int bid = blockIdx.x;
  const int seg = bid >> 11;             // 4 segments = 4 S row-slices (64MB each)
  const int sub = bid & 2047;
  const int mode = sub & 1, idx = sub >> 1;   // idx in [0,1024)
  const int tile0 = (mode == 0) ? (idx & 3) * 256 : seg * 256;  // r0 | l0
  const int fix   = (mode == 0) ? seg * 256 + (idx >> 2) : idx; // l  | r

  {
    const u16* Bp = (mode == 0 ? Qlb : Klb) + (size_t)fix * 4096;
    #pragma unroll
    for (int p = 0; p < 2; ++p) {
      int ci = t + p * 256, row = ci >> 3, c8 = (ci & 7) * 8;
      *reinterpret_cast<uint4*>(Bsm + row * 72 + c8) =
          *reinterpret_cast<const uint4*>(Bp + row * 64 + c8);
    }
  }
  __syncthreads();
  f32x4 acc[4][4] = {};
  #pragma unroll
  for (int ks = 0; ks < 2; ++ks) {
    float4 ld[8];
    #pragma unroll
    for (int fm = 0; fm < 4; ++fm) {
      const float* p = (mode == 0)
        ? S + ((size_t)fix * 1024 + tile0 + w * 64 + fm * 16 + lr) * 64 + ks * 32 + g * 8
        : S + ((size_t)(tile0 + w * 64 + fm * 16 + lr) << 16) + (size_t)fix * 64 + ks * 32 + g * 8;
      ld[fm * 2 + 0] = *reinterpret_cast<const float4*>(p);
      ld[fm * 2 + 1] = *reinterpret_cast<const float4*>(p + 4);
    }
    bf16x8 af[4], bo[4];
    #pragma unroll
    for (int fm = 0; fm < 4; ++fm) {
      bfr8 u;
      u.u[0] = f2bf(ld[fm * 2].x);     u.u[1] = f2bf(ld[fm * 2].y);
      u.u[2] = f2bf(ld[fm * 2].z);     u.u[3] = f2bf(ld[fm * 2].w);
      u.u[4] = f2bf(ld[fm * 2 + 1].x); u.u[5] = f2bf(ld[fm * 2 + 1].y);
      u.u[6] = f2bf(ld[fm * 2 + 1].z); u.u[7] = f2bf(ld[fm * 2 + 1].w);
      af[fm] = u.v;
    }
    #pragma unroll
    for (int fn = 0; fn < 4; ++fn)
      bo[fn] = *reinterpret_cast<const bf16x8*>(Bsm + (fn * 16 + lr) * 72 + ks * 32 + g * 8);
    #pragma unroll
    for (int fm = 0; fm < 4; ++fm)
      #pragma unroll
      for (int fn = 0; fn < 4; ++fn)
        acc[fm][fn] = __builtin_amdgcn_mfma_f32_16x16x32_bf16(af[fm], bo[fn], acc[fm][fn], 0, 0, 0);
  }
  const float scl = (mode == 0) ? 0.125f : 1.0f;
  #pragma unroll
  for (int fm = 0; fm < 4; ++fm)
    #pragma unroll
    for (int fn = 0; fn < 4; ++fn)
      #pragma unroll
      for (int i = 0; i < 4; ++i)
        stg[(fn * 16 + lr) * 264 + w * 64 + fm * 16 + g * 4 + i] = f2bf(acc[fm][fn][i] * scl);
  __syncthreads();
  {
    const int bh = t >> 2, seg2 = t & 3;
    u16* dst = (mode == 0)
      ? bias1 + ((size_t)bh << 21) + ((size_t)fix << 11) + tile0 + seg2 * 64
      : TB2 + ((size_t)bh << 20) + ((size_t)fix << 10) + tile0 + seg2 * 64;
    const u16* src = stg + bh * 264 + seg2 * 64;
    #pragma unroll
    for (int j = 0; j < 8; ++j)
      *reinterpret_cast<uint4*>(dst + j * 8) = *reinterpret_cast<const uint4*>(src + j * 8);
  }
}

// ---------------- K3: qk + bias merge + softmax + PV (R8 version) ----------
// one block per (bh, 32-l tile); r-tiles of 128 DESCENDING (bias1 packing).
__global__ __launch_bounds__(256) void k_qkpv(
    const u16* __restrict__ Qbh, const u16* __restrict__ Kbh,
    const u16* __restrict__ TB2, const u16* __restrict__ Vt,
    const float* __restrict__ mask, float* __restrict__ scores,
    u16* __restrict__ ctx)
{
  __shared__ __align__(16) u16 Qs[32 * 72];
  __shared__ __align__(16) u16 Ksm[128 * 72];   // reused as ctx f32 [32][66] in epilogue
  __shared__ __align__(16) u16 T2s[128 * 40];   // reused as ctx bf16 [32][64] in epilogue
  __shared__ __align__(16) u16 B1s[32 * 136];
  __shared__ __align__(16) u16 Vs[64 * 136];    // V transposed: [dh][r-tile 128]
  __shared__ float reds[32];
  __shared__ float ssum[32];
  const int t = threadIdx.x, w = t >> 6, lane = t & 63, g = lane >> 4, lr = lane & 15;
  const int bid = blockIdx.x;
  const int swz = (bid & 7) * 256 + (bid >> 3);   // XCD-chunked: same bh on one XCD
  const int bh = swz >> 5, l0 = (swz & 31) << 5;
  const u16* scores_u16 = reinterpret_cast<const u16*>(scores);
  {
    const u16* Qp = Qbh + ((size_t)bh << 16) + ((size_t)l0 << 6);
    int row = t >> 3, c8 = (t & 7) * 8;
    *reinterpret_cast<uint4*>(Qs + row * 72 + c8) =
        *reinterpret_cast<const uint4*>(Qp + (size_t)row * 64 + c8);
  }
  const int wr = w & 1, wc = w >> 1;
  const int l = l0 + wc * 16 + lr;
  const float* mrow = mask + ((size_t)(bh >> 4) << 10);
  float s = 0.f;
  f32x4 apv[4] = {};   // ctx partial: l = wc*16+g*4+i, dh = n*16+lr
  for (int r0 = 896; r0 >= 0; r0 -= 128) {
    {
      const u16* Kp = Kbh + ((size_t)bh << 16) + ((size_t)r0 << 6);
      #pragma unroll
      for (int p = 0; p < 4; ++p) {
        int ci = t + p * 256, row = ci >> 3, c8 = (ci & 7) * 8;
        *reinterpret_cast<uint4*>(Ksm + row * 72 + c8) =
            *reinterpret_cast<const uint4*>(Kp + (size_t)row * 64 + c8);
      }
    }
    {
      #pragma unroll
      for (int p = 0; p < 2; ++p) {
        int ci = t + p * 256, row = ci >> 2, c8 = (ci & 3) * 8;
        *reinterpret_cast<uint4*>(T2s + row * 40 + c8) =
            *reinterpret_cast<const uint4*>(TB2 + ((size_t)bh << 20) + ((size_t)(r0 + row) << 10) + l0 + c8);
      }
    }
    {
      #pragma unroll
      for (int p = 0; p < 2; ++p) {
        int ci = t + p * 256, row = ci >> 4, c8 = (ci & 15) * 8;
        *reinterpret_cast<uint4*>(B1s + row * 136 + c8) =
            *reinterpret_cast<const uint4*>(scores_u16 + ((size_t)bh << 21) + ((size_t)(l0 + row) << 11) + r0 + c8);
      }
    }
    {
      #pragma unroll
      for (int p = 0; p < 4; ++p) {
        int ci = t + p * 256, row = ci >> 4, c8 = (ci & 15) * 8;
        *reinterpret_cast<uint4*>(Vs + row * 136 + c8) =
            *reinterpret_cast<const uint4*>(Vt + ((size_t)bh << 16) + ((size_t)row << 10) + r0 + c8);
      }
    }
    __syncthreads();
    f32x4 acc[4] = {};
    #pragma unroll
    for (int ks = 0; ks < 2; ++ks) {
      bf16x8 bq = *reinterpret_cast<const bf16x8*>(Qs + (wc * 16 + lr) * 72 + ks * 32 + g * 8);
      #pragma unroll
      for (int fm = 0; fm < 4; ++fm) {
        bf16x8 ak = *reinterpret_cast<const bf16x8*>(Ksm + (wr * 64 + fm * 16 + lr) * 72 + ks * 32 + g * 8);
        acc[fm] = __builtin_amdgcn_mfma_f32_16x16x32_bf16(ak, bq, acc[fm], 0, 0, 0);
      }
    }
    float* srow = scores + ((size_t)bh << 20) + ((size_t)l << 10);
    u32 pL[4], pH[4];
    #pragma unroll
    for (int fm = 0; fm < 4; ++fm) {
      int rloc = wr * 64 + fm * 16 + g * 4;
      int rbase = r0 + rloc;
      float4 mv = *reinterpret_cast<const float4*>(mrow + rbase);
      float b20 = bf2f(T2s[(rloc + 0) * 40 + wc * 16 + lr]);
      float b21 = bf2f(T2s[(rloc + 1) * 40 + wc * 16 + lr]);
      float b22 = bf2f(T2s[(rloc + 2) * 40 + wc * 16 + lr]);
      float b23 = bf2f(T2s[(rloc + 3) * 40 + wc * 16 + lr]);
      uint2 b1p = *reinterpret_cast<const uint2*>(B1s + (wc * 16 + lr) * 136 + rloc);
      float b10 = bf2f((u16)(b1p.x & 0xffff)), b11 = bf2f((u16)(b1p.x >> 16));
      float b12 = bf2f((u16)(b1p.y & 0xffff)), b13 = bf2f((u16)(b1p.y >> 16));
      float4 o;
      o.x = (acc[fm][0] + b20) * 0.125f + b10 + mv.x;
      o.y = (acc[fm][1] + b21) * 0.125f + b11 + mv.y;
      o.z = (acc[fm][2] + b22) * 0.125f + b12 + mv.z;
      o.w = (acc[fm][3] + b23) * 0.125f + b13 + mv.w;
      *reinterpret_cast<float4*>(srow + rbase) = o;
      float p0 = __expf(o.x), p1 = __expf(o.y), p2 = __expf(o.z), p3 = __expf(o.w);
      s += p0 + p1 + p2 + p3;
      pL[fm] = (u32)f2bf(p0) | ((u32)f2bf(p1) << 16);
      pH[fm] = (u32)f2bf(p2) | ((u32)f2bf(p3) << 16);
    }
    // PV: A-frag slots (g,j): r = wr*64 + t2*32 + (j>>2)*16 + g*4 + (j&3)
    #pragma unroll
    for (int t2 = 0; t2 < 2; ++t2) {
      bfr8 a;
      a.w[0] = pL[2 * t2];     a.w[1] = pH[2 * t2];
      a.w[2] = pL[2 * t2 + 1]; a.w[3] = pH[2 * t2 + 1];
      #pragma unroll
      for (int n = 0; n < 4; ++n) {
        const u16* vb = Vs + (n * 16 + lr) * 136 + wr * 64 + t2 * 32 + g * 4;
        uint2 v0 = *reinterpret_cast<const uint2*>(vb);
        uint2 v1 = *reinterpret_cast<const uint2*>(vb + 16);
        bfr8 b;
        b.w[0] = v0.x; b.w[1] = v0.y; b.w[2] = v1.x; b.w[3] = v1.y;
        apv[n] = __builtin_amdgcn_mfma_f32_16x16x32_bf16(a.v, b.v, apv[n], 0, 0, 0);
      }
    }
    __syncthreads();
  }
  // row-sum reduce: across g within wave, then across wr pair via LDS
  #pragma unroll
  for (int off = 16; off < 64; off <<= 1) s += __shfl_xor(s, off);
  if (wr == 1 && lane < 16) reds[wc * 16 + lr] = s;
  __syncthreads();
  if (wr == 0 && lane < 16) ssum[wc * 16 + lr] = 1.0f / (s + reds[wc * 16 + lr]);
  // ctx cross-wave reduce in LDS (reuse Ksm as f32 [32][66], T2s as bf16 [32][64])
  float* c32 = reinterpret_cast<float*>(Ksm);
  u16* cb = T2s;
  if (wr == 1) {
    #pragma unroll
    for (int n = 0; n < 4; ++n)
      #pragma unroll
      for (int i = 0; i < 4; ++i)
        c32[(wc * 16 + g * 4 + i) * 66 + n * 16 + lr] = apv[n][i];
  }
  __syncthreads();
  if (wr == 0) {
    #pragma unroll
    for (int n = 0; n < 4; ++n)
      #pragma unroll
      for (int i = 0; i < 4; ++i) {
        int li = wc * 16 + g * 4 + i;
        float v = apv[n][i] + c32[li * 66 + n * 16 + lr];
        cb[li * 64 + n * 16 + lr] = f2bf(v * ssum[li]);
      }
  }
  __syncthreads();
  {
    int row = t >> 3, c8 = (t & 7) * 8;
    const int b = bh >> 4, h = bh & 15;
    uint4 vv = *reinterpret_cast<const uint4*>(cb + row * 64 + c8);
    *reinterpret_cast<uint4*>(ctx + ((size_t)(b * 1024 + l0 + row) << 10) + (h << 6) + c8) = vv;
  }
}

// ---------------- K6: out-proj + bias + residual ----------------
__global__ __launch_bounds__(256) void k_outproj(
    const u16* __restrict__ ctx, const float* __restrict__ Wd,
    const float* __restrict__ bd, const float* __restrict__ Xq,
    float* __restrict__ y)
{
  __shared__ __align__(16) u16 As_[128 * 72];
  __shared__ __align__(16) u16 Bs_[128 * 72];
  const int t = threadIdx.x, w = t >> 6, lane = t & 63, g = lane >> 4, lr = lane & 15;
  const int o0 = blockIdx.x * 128, n0 = blockIdx.y * 128;
  const int wr = w >> 1, wc = w & 1;
  f32x4 acc[4][4] = {};
  for (int k0 = 0; k0 < 1024; k0 += 64) {
    for (int p = 0; p < 8; ++p) {
      int fi = t + p * 256, row = fi >> 4, c4 = (fi & 15) * 4;
      float4 v = *reinterpret_cast<const float4*>(Wd + (size_t)(o0 + row) * 1024 + k0 + c4);
      u16* d = As_ + row * 72 + c4;
      d[0] = f2bf(v.x); d[1] = f2bf(v.y); d[2] = f2bf(v.z); d[3] = f2bf(v.w);
    }
    for (int p = 0; p < 4; ++p) {
      int ci = t + p * 256, row = ci >> 3, c8 = (ci & 7) * 8;
      *reinterpret_cast<uint4*>(Bs_ + row * 72 + c8) =
          *reinterpret_cast<const uint4*>(ctx + (size_t)(n0 + row) * 1024 + k0 + c8);
    }
    __syncthreads();
    #pragma unroll
    for (int ks = 0; ks < 2; ++ks) {
      bf16x8 af[4], bfr[4];
      #pragma unroll
      for (int fm = 0; fm < 4; ++fm)
        af[fm] = *reinterpret_cast<const bf16x8*>(As_ + (wr * 64 + fm * 16 + lr) * 72 + ks * 32 + g * 8);
      #pragma unroll
      for (int fn = 0; fn < 4; ++fn)
        bfr[fn] = *reinterpret_cast<const bf16x8*>(Bs_ + (wc * 64 + fn * 16 + lr) * 72 + ks * 32 + g * 8);
      #pragma unroll
      for (int fm = 0; fm < 4; ++fm)
        #pragma unroll
        for (int fn = 0; fn < 4; ++fn)
          acc[fm][fn] = __builtin_amdgcn_mfma_f32_16x16x32_bf16(af[fm], bfr[fn], acc[fm][fn], 0, 0, 0);
    }
    __syncthreads();
  }
  #pragma unroll
  for (int fm = 0; fm < 4; ++fm)
    #pragma unroll
    for (int fn = 0; fn < 4; ++fn) {
      int obase = o0 + wr * 64 + fm * 16 + g * 4;
      int n = n0 + wc * 64 + fn * 16 + lr;
      float4 bb = *reinterpret_cast<const float4*>(bd + obase);
      float4 xx = *reinterpret_cast<const float4*>(Xq + (size_t)n * 1024 + obase);
      float4 o;
      o.x = acc[fm][fn][0] + bb.x + xx.x;
      o.y = acc[fm][fn][1] + bb.y + xx.y;
      o.z = acc[fm][fn][2] + bb.z + xx.z;
      o.w = acc[fm][fn][3] + bb.w + xx.w;
      *reinterpret_cast<float4*>(y + (size_t)n * 1024 + obase) = o;
    }
}

// ---------------- K7: in-place LayerNorm ----------------
__global__ __launch_bounds__(256) void k_ln(
    float* __restrict__ y, const float* __restrict__ gam,
    const float* __restrict__ bet)
{
  __shared__ float red[8];
  const int t = threadIdx.x, w = t >> 6, lane = t & 63;
  float* row = y + ((size_t)blockIdx.x << 10);
  float4 v = *reinterpret_cast<const float4*>(row + t * 4);
  float s1 = v.x + v.y + v.z + v.w;
  float s2 = v.x * v.x + v.y * v.y + v.z * v.z + v.w * v.w;
  #pragma unroll
  for (int s = 1; s < 64; s <<= 1) { s1 += __shfl_xor(s1, s); s2 += __shfl_xor(s2, s); }
  if (lane == 0) { red[w] = s1; red[4 + w] = s2; }
  __syncthreads();
  s1 = red[0] + red[1] + red[2] + red[3];
  s2 = red[4] + red[5] + red[6] + red[7];
  float mu = s1 * (1.0f / 1024.0f);
  float var = s2 * (1.0f / 1024.0f) - mu * mu;
  float rs = rsqrtf(var + 1e-5f);
  float4 gg = *reinterpret_cast<const float4*>(gam + t * 4);
  float4 bb = *reinterpret_cast<const float4*>(bet + t * 4);
  float4 o;
  o.x = (v.x - mu) * rs * gg.x + bb.x;
  o.y = (v.y - mu) * rs * gg.y + bb.y;
  o.z = (v.z - mu) * rs * gg.z + bb.z;
  o.w = (v.w - mu) * rs * gg.w + bb.w;
  *reinterpret_cast<float4*>(row + t * 4) = o;
}

extern "C" void kernel_launch(void* const* d_in, const int* in_sizes, int n_in,
                              void* d_out, int out_size, void* d_ws, size_t ws_size,
                              hipStream_t stream) {
  (void)in_sizes; (void)n_in; (void)out_size; (void)ws_size;
  const float* Xq   = (const float*)d_in[0];
  const float* Xv   = (const float*)d_in[1];
  const float* mask = (const float*)d_in[2];
  const float* S    = (const float*)d_in[3];
  const float* Wq   = (const float*)d_in[4];
  const float* bq   = (const float*)d_in[5];
  const float* Wk   = (const float*)d_in[6];
  const float* bk   = (const float*)d_in[7];
  const float* Wv   = (const float*)d_in[8];
  const float* bv   = (const float*)d_in[9];
  const float* Wd   = (const float*)d_in[10];
  const float* bd   = (const float*)d_in[11];
  const float* gam  = (const float*)d_in[12];
  const float* bet  = (const float*)d_in[13];

  float* out    = (float*)d_out;
  float* scores = out + (size_t)4 * 1024 * 1024;
  u16* scores_u16 = (u16*)scores;

  char* ws = (char*)d_ws;
  u16* Qbh = (u16*)(ws);
  u16* Kbh = (u16*)(ws + ((size_t)8 << 20));
  u16* Vt  = (u16*)(ws + ((size_t)16 << 20));
  u16* Qlb = (u16*)(ws + ((size_t)24 << 20));
  u16* Klb = (u16*)(ws + ((size_t)32 << 20));
  u16* TB2 = (u16*)(ws + ((size_t)40 << 20));
  u16* ctx = (u16*)(ws + ((size_t)169 << 20));

  k_proj<<<dim3(32, 8, 3), 256, 0, stream>>>(Xq, Xv, Wq, bq, Wk, bk, Wv, bv,
                                             Qbh, Qlb, Kbh, Klb, Vt);
  k_biasqk<<<8192, 256, 0, stream>>>(S, Qlb, Klb, scores_u16, TB2);
  k_qkpv<<<2048, 256, 0, stream>>>(Qbh, Kbh, TB2, Vt, mask, scores, ctx);
  k_outproj<<<dim3(8, 32), 256, 0, stream>>>(ctx, Wd, bd, Xq, out);
  k_ln<<<4096, 256, 0, stream>>>(out, gam, bet);
}